// Round 1
// baseline (2072.046 us; speedup 1.0000x reference)
//
#include <hip/hip_runtime.h>

#define BATCH 4096
#define T 256
#define IN 64
#define CELL 128
#define ZDIM 256
#define OUTD 64
#define ROWS 8

__global__ __launch_bounds__(256, 2)
void llrnn_fused(const float* __restrict__ in,     // [B,T,IN]
                 const float* __restrict__ Km,     // [IN,ZDIM]
                 const float* __restrict__ Rm,     // [CELL,ZDIM]
                 const float* __restrict__ bz,     // [ZDIM]
                 const float* __restrict__ Wd,     // [CELL,OUTD]
                 const float* __restrict__ bd,     // [OUTD]
                 float* __restrict__ out)          // [B,OUTD]
{
  __shared__ __align__(16) float c_lds[ROWS][CELL];
  __shared__ __align__(16) float z_lds[ROWS][ZDIM];
  __shared__ __align__(16) float x_lds[2][ROWS][IN];

  const int tid = threadIdx.x;
  const int j = tid;                 // z-column 0..255
  const int rb = blockIdx.x * ROWS;  // batch row base

  // ---- preload weight columns into registers ----
  float kw[IN];
  #pragma unroll
  for (int i = 0; i < IN; ++i) kw[i] = Km[i * ZDIM + j];
  float rw[CELL];
  #pragma unroll
  for (int k = 0; k < CELL; ++k) rw[k] = Rm[k * ZDIM + j];
  const float bias_j = bz[j];

  // ---- init c = 0, stage x(t=0) ----
  #pragma unroll
  for (int q = 0; q < (ROWS * CELL) / 256; ++q)
    ((float*)c_lds)[tid + 256 * q] = 0.f;
  {
    const int r = tid >> 5;            // 8 rows, 32 threads each
    const int col = (tid & 31) * 2;
    const float2 v = *(const float2*)(in + ((size_t)(rb + r) * T + 0) * IN + col);
    *(float2*)&x_lds[0][r][col] = v;
  }
  __syncthreads();

  const int sr = tid >> 5;
  const int scol = (tid & 31) * 2;
  const float* sptr = in + ((size_t)(rb + sr) * T + 1) * IN + scol;

  for (int t = 0; t < T; ++t) {
    // issue global load of x(t+1) early; used after barrier
    float p0 = 0.f, p1 = 0.f;
    if (t + 1 < T) {
      const float2 v = *(const float2*)sptr;
      p0 = v.x; p1 = v.y;
      sptr += IN;
    }
    const float (*xA)[IN] = x_lds[t & 1];

    float acc[ROWS];
    #pragma unroll
    for (int r = 0; r < ROWS; ++r) acc[r] = bias_j;

    // input projection: z += K[:,j] . x
    #pragma unroll
    for (int i = 0; i < IN; i += 4) {
      #pragma unroll
      for (int r = 0; r < ROWS; ++r) {
        const float4 xv = *(const float4*)&xA[r][i];
        acc[r] += kw[i] * xv.x + kw[i+1] * xv.y + kw[i+2] * xv.z + kw[i+3] * xv.w;
      }
    }
    // recurrent: z += R[:,j] . c
    #pragma unroll
    for (int k = 0; k < CELL; k += 4) {
      #pragma unroll
      for (int r = 0; r < ROWS; ++r) {
        const float4 cv = *(const float4*)&c_lds[r][k];
        acc[r] += rw[k] * cv.x + rw[k+1] * cv.y + rw[k+2] * cv.z + rw[k+3] * cv.w;
      }
    }

    #pragma unroll
    for (int r = 0; r < ROWS; ++r) z_lds[r][j] = acc[r];
    __syncthreads();

    // write x(t+1) into the other buffer
    if (t + 1 < T) {
      x_lds[(t + 1) & 1][sr][scol]     = p0;
      x_lds[(t + 1) & 1][sr][scol + 1] = p1;
    }

    // gated cell update: each thread owns 4 cells
    #pragma unroll
    for (int q = 0; q < (ROWS * CELL) / 256; ++q) {
      const int cell = tid + 256 * q;
      const int r = cell >> 7;
      const int k = cell & 127;
      const float zf = z_lds[r][k];
      float zg = z_lds[r][k + CELL];
      zg = fminf(fmaxf(zg, -15.f), 15.f);
      const float f = 1.f / (1.f + __expf(-zf));
      const float e = __expf(2.f * zg);
      const float th = (e - 1.f) / (e + 1.f);
      c_lds[r][k] = f * c_lds[r][k] + (1.f - f) * th;
    }
    __syncthreads();
  }

  // ---- dense epilogue: out = h @ Wd + bd ----
  const int o = tid & 63;
  const int rr = tid >> 6;   // 0..3, handles rows rr and rr+4
  float a0 = bd[o], a1 = bd[o];
  #pragma unroll
  for (int k = 0; k < CELL; ++k) {
    const float w = Wd[k * OUTD + o];
    a0 += c_lds[rr][k]     * w;
    a1 += c_lds[rr + 4][k] * w;
  }
  out[(size_t)(rb + rr) * OUTD + o] = a0;
  out[(size_t)(rb + rr + 4) * OUTD + o] = a1;
}

extern "C" void kernel_launch(void* const* d_in, const int* in_sizes, int n_in,
                              void* d_out, int out_size, void* d_ws, size_t ws_size,
                              hipStream_t stream) {
  const float* in  = (const float*)d_in[0];
  const float* Km  = (const float*)d_in[1];
  const float* Rm  = (const float*)d_in[2];
  const float* bz  = (const float*)d_in[3];
  const float* Wd  = (const float*)d_in[4];
  const float* bd  = (const float*)d_in[5];
  float* out = (float*)d_out;

  dim3 grid(BATCH / ROWS);   // 512 blocks
  dim3 block(256);
  hipLaunchKernelGGL(llrnn_fused, grid, block, 0, stream,
                     in, Km, Rm, bz, Wd, bd, out);
}

// Round 2
// 450.967 us; speedup vs baseline: 4.5947x; 4.5947x over previous
//
#include <hip/hip_runtime.h>

#define BATCH 4096
#define T 256
#define IN 64
#define CELL 128
#define ZDIM 256
#define OUTD 64
#define M 16   // batch rows per block

using f32x4  = __attribute__((ext_vector_type(4))) float;
using f32x4v = __attribute__((ext_vector_type(4))) float;
using s16x8  = __attribute__((ext_vector_type(8))) short;
typedef unsigned short ushort_t;
typedef unsigned int   uint_t;

__device__ __forceinline__ ushort_t f2bf(float f) {
  uint_t u = __float_as_uint(f);
  u += 0x7fffu + ((u >> 16) & 1u);   // round-to-nearest-even
  return (ushort_t)(u >> 16);
}
__device__ __forceinline__ float bf2f(ushort_t h) {
  return __uint_as_float(((uint_t)h) << 16);
}

// split two float4s (8 consecutive k-elements) into hi/lo bf16 fragments
__device__ __forceinline__ void split8(const f32x4v a, const f32x4v b,
                                       s16x8& hi, s16x8& lo) {
#pragma unroll
  for (int e = 0; e < 4; ++e) {
    float v = a[e];
    ushort_t h = f2bf(v);
    hi[e] = (short)h;
    lo[e] = (short)f2bf(v - bf2f(h));
    float v2 = b[e];
    ushort_t h2 = f2bf(v2);
    hi[e + 4] = (short)h2;
    lo[e + 4] = (short)f2bf(v2 - bf2f(h2));
  }
}

#define MM3(AH, AL, KT)                                                        \
  accf = __builtin_amdgcn_mfma_f32_16x16x32_bf16(AH, bhf[KT], accf, 0, 0, 0);  \
  accg = __builtin_amdgcn_mfma_f32_16x16x32_bf16(AH, bhg[KT], accg, 0, 0, 0);  \
  accf = __builtin_amdgcn_mfma_f32_16x16x32_bf16(AL, bhf[KT], accf, 0, 0, 0);  \
  accg = __builtin_amdgcn_mfma_f32_16x16x32_bf16(AL, bhg[KT], accg, 0, 0, 0);  \
  accf = __builtin_amdgcn_mfma_f32_16x16x32_bf16(AH, blf[KT], accf, 0, 0, 0);  \
  accg = __builtin_amdgcn_mfma_f32_16x16x32_bf16(AH, blg[KT], accg, 0, 0, 0);

// One recurrence step. Reads c from buf P, writes c' to buf P^1.
// XC* hold x(t) raw floats; prefetches x(t+1) into XN*.
#define STEP(XC0, XC1, XC2, XC3, XN0, XN1, XN2, XN3, TT, P)                    \
  {                                                                            \
    f32x4 accf = {biasf, biasf, biasf, biasf};                                 \
    f32x4 accg = {biasg, biasg, biasg, biasg};                                 \
    s16x8 xh0, xl0, xh1, xl1;                                                  \
    split8(XC0, XC1, xh0, xl0);                                                \
    split8(XC2, XC3, xh1, xl1);                                                \
    const char* hb = (const char*)cb_hi[P] + q * 256;                          \
    const char* lb = (const char*)cb_lo[P] + q * 256;                          \
    s16x8 ch0 = *(const s16x8*)(hb + ((0 + 16 * g) ^ swzq));                   \
    s16x8 ch1 = *(const s16x8*)(hb + ((64 + 16 * g) ^ swzq));                  \
    s16x8 ch2 = *(const s16x8*)(hb + ((128 + 16 * g) ^ swzq));                 \
    s16x8 ch3 = *(const s16x8*)(hb + ((192 + 16 * g) ^ swzq));                 \
    s16x8 cl0 = *(const s16x8*)(lb + ((0 + 16 * g) ^ swzq));                   \
    s16x8 cl1 = *(const s16x8*)(lb + ((64 + 16 * g) ^ swzq));                  \
    s16x8 cl2 = *(const s16x8*)(lb + ((128 + 16 * g) ^ swzq));                 \
    s16x8 cl3 = *(const s16x8*)(lb + ((192 + 16 * g) ^ swzq));                 \
    {                                                                          \
      int tn = (TT) + 1 < T ? (TT) + 1 : T - 1;                                \
      const float* xp = xrow + (size_t)tn * IN;                                \
      XN0 = *(const f32x4v*)(xp + 8 * g);                                      \
      XN1 = *(const f32x4v*)(xp + 8 * g + 4);                                  \
      XN2 = *(const f32x4v*)(xp + 32 + 8 * g);                                 \
      XN3 = *(const f32x4v*)(xp + 32 + 8 * g + 4);                             \
    }                                                                          \
    MM3(xh0, xl0, 0)                                                           \
    MM3(xh1, xl1, 1)                                                           \
    MM3(ch0, cl0, 2)                                                           \
    MM3(ch1, cl1, 3)                                                           \
    MM3(ch2, cl2, 4)                                                           \
    MM3(ch3, cl3, 5)                                                           \
    _Pragma("unroll")                                                          \
    for (int i = 0; i < 4; ++i) {                                              \
      float zf = accf[i];                                                      \
      float zg = accg[i];                                                      \
      zg = fminf(fmaxf(zg, -15.f), 15.f);                                      \
      float fg = 1.f / (1.f + __expf(-zf));                                    \
      float e2 = __expf(2.f * zg);                                             \
      float th = (e2 - 1.f) / (e2 + 1.f);                                      \
      float cn = fg * (creg[i] - th) + th;                                     \
      creg[i] = cn;                                                            \
      ushort_t hh = f2bf(cn);                                                  \
      ushort_t ll = f2bf(cn - bf2f(hh));                                       \
      int row = 4 * g + i;                                                     \
      int wb = row * 256 + ((32 * w + 2 * q) ^ ((row & 7) << 4));              \
      *(ushort_t*)((char*)cb_hi[(P) ^ 1] + wb) = hh;                           \
      *(ushort_t*)((char*)cb_lo[(P) ^ 1] + wb) = ll;                           \
    }                                                                          \
    __syncthreads();                                                           \
  }

__global__ __launch_bounds__(512, 2)
void llrnn_mfma(const float* __restrict__ in,   // [B,T,IN]
                const float* __restrict__ Km,   // [IN,ZDIM]
                const float* __restrict__ Rm,   // [CELL,ZDIM]
                const float* __restrict__ bz,   // [ZDIM]
                const float* __restrict__ Wd,   // [CELL,OUTD]
                const float* __restrict__ bd,   // [OUTD]
                float* __restrict__ out)        // [B,OUTD]
{
  // split-bf16 c state, double buffered, XOR-swizzled rows (16 x 128 bf16)
  __shared__ ushort_t cb_hi[2][M * CELL];
  __shared__ ushort_t cb_lo[2][M * CELL];
  __shared__ float cfin[M * CELL];

  const int tid = threadIdx.x;
  const int w = tid >> 6;        // wave 0..7, owns z-cols [16w,16w+16) and +128
  const int l = tid & 63;
  const int q = l & 15;          // A row / B,D col within tile
  const int g = l >> 4;          // k-group 0..3
  const int rb = blockIdx.x * M; // batch row base
  const int jf = 16 * w + q;     // forget-gate column
  const int jg = jf + CELL;      // cell-input column
  const int swzq = (q & 7) << 4;

  // zero c buffers (t=0 state, buf 0 read first; zero both for safety)
  {
    uint_t* z0 = (uint_t*)cb_hi[0];
    uint_t* z1 = (uint_t*)cb_lo[0];
    z0[tid] = 0; z0[tid + 512] = 0;
    z1[tid] = 0; z1[tid + 512] = 0;
  }

  // ---- preload B = [K; R] columns jf, jg as split-bf16 fragments ----
  s16x8 bhf[6], blf[6], bhg[6], blg[6];
#pragma unroll
  for (int kt = 0; kt < 6; ++kt) {
#pragma unroll
    for (int e = 0; e < 8; ++e) {
      const int krow = 32 * kt + 8 * g + e;
      const float* src = (kt < 2) ? (Km + (size_t)krow * ZDIM)
                                  : (Rm + (size_t)(krow - IN) * ZDIM);
      float vf = src[jf];
      float vg = src[jg];
      ushort_t h;
      h = f2bf(vf); bhf[kt][e] = (short)h; blf[kt][e] = (short)f2bf(vf - bf2f(h));
      h = f2bf(vg); bhg[kt][e] = (short)h; blg[kt][e] = (short)f2bf(vg - bf2f(h));
    }
  }
  const float biasf = bz[jf];
  const float biasg = bz[jg];

  const float* xrow = in + (size_t)(rb + q) * T * IN;
  f32x4v xc0, xc1, xc2, xc3, xn0, xn1, xn2, xn3;
  xc0 = *(const f32x4v*)(xrow + 8 * g);
  xc1 = *(const f32x4v*)(xrow + 8 * g + 4);
  xc2 = *(const f32x4v*)(xrow + 32 + 8 * g);
  xc3 = *(const f32x4v*)(xrow + 32 + 8 * g + 4);

  float creg[4] = {0.f, 0.f, 0.f, 0.f};  // fp32 master state, D-layout

  __syncthreads();

  for (int t = 0; t < T; t += 2) {
    STEP(xc0, xc1, xc2, xc3, xn0, xn1, xn2, xn3, t, 0)
    STEP(xn0, xn1, xn2, xn3, xc0, xc1, xc2, xc3, t + 1, 1)
  }

  // ---- write final c (fp32) and dense epilogue ----
#pragma unroll
  for (int i = 0; i < 4; ++i)
    cfin[(4 * g + i) * CELL + jf] = creg[i];
  __syncthreads();

  const int o = tid & 63;
  const int rp = tid >> 6;  // rows rp and rp+8
  float a0 = bd[o], a1 = bd[o];
#pragma unroll 4
  for (int k = 0; k < CELL; ++k) {
    const float wv = Wd[(size_t)k * OUTD + o];
    a0 += cfin[rp * CELL + k] * wv;
    a1 += cfin[(rp + 8) * CELL + k] * wv;
  }
  out[(size_t)(rb + rp) * OUTD + o] = a0;
  out[(size_t)(rb + rp + 8) * OUTD + o] = a1;
}

extern "C" void kernel_launch(void* const* d_in, const int* in_sizes, int n_in,
                              void* d_out, int out_size, void* d_ws, size_t ws_size,
                              hipStream_t stream) {
  const float* in  = (const float*)d_in[0];
  const float* Km  = (const float*)d_in[1];
  const float* Rm  = (const float*)d_in[2];
  const float* bz  = (const float*)d_in[3];
  const float* Wd  = (const float*)d_in[4];
  const float* bd  = (const float*)d_in[5];
  float* out = (float*)d_out;

  dim3 grid(BATCH / M);   // 256 blocks -> 1 per CU
  dim3 block(512);        // 8 waves, 2 per SIMD
  hipLaunchKernelGGL(llrnn_mfma, grid, block, 0, stream,
                     in, Km, Rm, bz, Wd, bd, out);
}

// Round 3
// 326.265 us; speedup vs baseline: 6.3508x; 1.3822x over previous
//
#include <hip/hip_runtime.h>

#define BATCH 4096
#define T 256
#define IN 64
#define CELL 128
#define ZDIM 256
#define OUTD 64
#define M 16   // batch rows per block (one MFMA row-tile)

using f32x4 = __attribute__((ext_vector_type(4))) float;
using f4    = __attribute__((ext_vector_type(4))) float;
using h16x8 = __attribute__((ext_vector_type(8))) _Float16;
typedef unsigned int u32t;

// One recurrence step. Reads c(fp16) from cbuf[P], writes c'(fp16) to cbuf[P^1].
// XC* = raw fp32 x(t) (prefetched last step); prefetches x(t+1) into XN*.
#define STEP(XC0, XC1, XC2, XC3, XN0, XN1, XN2, XN3, TT, P)                     \
  {                                                                             \
    /* prefetch x(t+1) first: longest latency, needed latest */                 \
    {                                                                           \
      int tn = (TT) + 1 < T ? (TT) + 1 : T - 1;                                 \
      const float* xp = xrow + (size_t)tn * IN;                                 \
      XN0 = *(const f4*)(xp + 8 * g);                                           \
      XN1 = *(const f4*)(xp + 8 * g + 4);                                       \
      XN2 = *(const f4*)(xp + 32 + 8 * g);                                      \
      XN3 = *(const f4*)(xp + 32 + 8 * g + 4);                                  \
    }                                                                           \
    /* issue c-frag LDS reads early */                                          \
    const char* cb_ = cbuf[P];                                                  \
    h16x8 ca0 = *(const h16x8*)(cb_ + ro[0]);                                   \
    h16x8 ca1 = *(const h16x8*)(cb_ + ro[1]);                                   \
    h16x8 ca2 = *(const h16x8*)(cb_ + ro[2]);                                   \
    h16x8 ca3 = *(const h16x8*)(cb_ + ro[3]);                                   \
    /* convert x(t) to fp16 A-frags while LDS returns */                        \
    h16x8 xa0, xa1;                                                             \
    _Pragma("unroll") for (int e = 0; e < 4; ++e) {                             \
      xa0[e]     = (_Float16)XC0[e];                                            \
      xa0[e + 4] = (_Float16)XC1[e];                                            \
      xa1[e]     = (_Float16)XC2[e];                                            \
      xa1[e + 4] = (_Float16)XC3[e];                                            \
    }                                                                           \
    f32x4 accf = {biasf, biasf, biasf, biasf};                                  \
    f32x4 accg = {biasg, biasg, biasg, biasg};                                  \
    accf = __builtin_amdgcn_mfma_f32_16x16x32_f16(xa0, bhf[0], accf, 0, 0, 0);  \
    accg = __builtin_amdgcn_mfma_f32_16x16x32_f16(xa0, bhg[0], accg, 0, 0, 0);  \
    accf = __builtin_amdgcn_mfma_f32_16x16x32_f16(xa1, bhf[1], accf, 0, 0, 0);  \
    accg = __builtin_amdgcn_mfma_f32_16x16x32_f16(xa1, bhg[1], accg, 0, 0, 0);  \
    accf = __builtin_amdgcn_mfma_f32_16x16x32_f16(ca0, bhf[2], accf, 0, 0, 0);  \
    accg = __builtin_amdgcn_mfma_f32_16x16x32_f16(ca0, bhg[2], accg, 0, 0, 0);  \
    accf = __builtin_amdgcn_mfma_f32_16x16x32_f16(ca1, bhf[3], accf, 0, 0, 0);  \
    accg = __builtin_amdgcn_mfma_f32_16x16x32_f16(ca1, bhg[3], accg, 0, 0, 0);  \
    accf = __builtin_amdgcn_mfma_f32_16x16x32_f16(ca2, bhf[4], accf, 0, 0, 0);  \
    accg = __builtin_amdgcn_mfma_f32_16x16x32_f16(ca2, bhg[4], accg, 0, 0, 0);  \
    accf = __builtin_amdgcn_mfma_f32_16x16x32_f16(ca3, bhf[5], accf, 0, 0, 0);  \
    accg = __builtin_amdgcn_mfma_f32_16x16x32_f16(ca3, bhg[5], accg, 0, 0, 0);  \
    /* gates: f = sigmoid(zf), th = tanh(zg); inf-safe, no clamp needed */      \
    char* cn_ = cbuf[(P) ^ 1];                                                  \
    _Pragma("unroll") for (int i = 0; i < 4; ++i) {                             \
      float zf = accf[i], zg = accg[i];                                         \
      float fg = __builtin_amdgcn_rcpf(1.f + __expf(-zf));                      \
      float th = 1.f - 2.f * __builtin_amdgcn_rcpf(__expf(2.f * zg) + 1.f);     \
      float cn = fg * (creg[i] - th) + th;                                      \
      creg[i] = cn;                                                             \
      *(_Float16*)(cn_ + wo[i]) = (_Float16)cn;                                 \
    }                                                                           \
    __syncthreads();                                                            \
  }

__global__ __launch_bounds__(512, 2)
void llrnn_f16(const float* __restrict__ in,   // [B,T,IN]
               const float* __restrict__ Km,   // [IN,ZDIM]
               const float* __restrict__ Rm,   // [CELL,ZDIM]
               const float* __restrict__ bz,   // [ZDIM]
               const float* __restrict__ Wd,   // [CELL,OUTD]
               const float* __restrict__ bd,   // [OUTD]
               float* __restrict__ out)        // [B,OUTD]
{
  // c state as fp16 [16 rows][128 cells], chunk-XOR-swizzled, double-buffered.
  // byte(row, k) = row*256 + 16*(((2k)>>4) ^ (row&7)) + ((2k)&15)
  __shared__ __align__(16) char cbuf[2][M * CELL * 2];   // 2 x 4 KB
  __shared__ float cfin[M * CELL];

  const int tid = threadIdx.x;
  const int w = tid >> 6;        // wave 0..7: owns z-cols [16w,16w+16) and +128
  const int l = tid & 63;
  const int q = l & 15;          // A-row / D-col within tile
  const int g = l >> 4;          // k-group 0..3
  const int rb = blockIdx.x * M;
  const int jf = 16 * w + q;     // forget-gate column
  const int jg = jf + CELL;      // cell-input column

  // zero c(t=0) buffer
  ((u32t*)cbuf[0])[tid] = 0;
  ((u32t*)cbuf[0])[tid + 512] = 0;

  // ---- preload B = [K; R] columns jf, jg as fp16 fragments (48 VGPR) ----
  h16x8 bhf[6], bhg[6];
#pragma unroll
  for (int kt = 0; kt < 6; ++kt) {
#pragma unroll
    for (int e = 0; e < 8; ++e) {
      const int krow = 32 * kt + 8 * g + e;
      const float* src = (kt < 2) ? (Km + (size_t)krow * ZDIM)
                                  : (Rm + (size_t)(krow - IN) * ZDIM);
      bhf[kt][e] = (_Float16)src[jf];
      bhg[kt][e] = (_Float16)src[jg];
    }
  }
  const float biasf = bz[jf];
  const float biasg = bz[jg];

  // precomputed LDS byte offsets
  int ro[4];   // read: c frag kt, row q, k = 32*kt + 8g .. +8
#pragma unroll
  for (int ct = 0; ct < 4; ++ct)
    ro[ct] = q * 256 + 16 * ((4 * ct + g) ^ (q & 7));
  int wo[4];   // write: cell (row 4g+i, k = jf)
#pragma unroll
  for (int i = 0; i < 4; ++i) {
    const int r = 4 * g + i;
    wo[i] = r * 256 + 16 * ((2 * w + (q >> 3)) ^ (r & 7)) + 2 * (q & 7);
  }

  const float* xrow = in + (size_t)(rb + q) * T * IN;
  f4 xc0 = *(const f4*)(xrow + 8 * g);
  f4 xc1 = *(const f4*)(xrow + 8 * g + 4);
  f4 xc2 = *(const f4*)(xrow + 32 + 8 * g);
  f4 xc3 = *(const f4*)(xrow + 32 + 8 * g + 4);
  f4 xn0, xn1, xn2, xn3;

  float creg[4] = {0.f, 0.f, 0.f, 0.f};  // fp32 master state (D-layout)

  __syncthreads();

  for (int t = 0; t < T; t += 2) {
    STEP(xc0, xc1, xc2, xc3, xn0, xn1, xn2, xn3, t, 0)
    STEP(xn0, xn1, xn2, xn3, xc0, xc1, xc2, xc3, t + 1, 1)
  }

  // ---- final c (fp32) to LDS, dense epilogue out = h @ Wd + bd ----
#pragma unroll
  for (int i = 0; i < 4; ++i)
    cfin[(4 * g + i) * CELL + jf] = creg[i];
  __syncthreads();

  const int o = tid & 63;
  const int rp = tid >> 6;  // rows rp and rp+8
  float a0 = bd[o], a1 = bd[o];
#pragma unroll 4
  for (int k = 0; k < CELL; ++k) {
    const float wv = Wd[(size_t)k * OUTD + o];
    a0 += cfin[rp * CELL + k] * wv;
    a1 += cfin[(rp + 8) * CELL + k] * wv;
  }
  out[(size_t)(rb + rp) * OUTD + o] = a0;
  out[(size_t)(rb + rp + 8) * OUTD + o] = a1;
}

extern "C" void kernel_launch(void* const* d_in, const int* in_sizes, int n_in,
                              void* d_out, int out_size, void* d_ws, size_t ws_size,
                              hipStream_t stream) {
  const float* in  = (const float*)d_in[0];
  const float* Km  = (const float*)d_in[1];
  const float* Rm  = (const float*)d_in[2];
  const float* bz  = (const float*)d_in[3];
  const float* Wd  = (const float*)d_in[4];
  const float* bd  = (const float*)d_in[5];
  float* out = (float*)d_out;

  dim3 grid(BATCH / M);   // 256 blocks -> 1 per CU
  dim3 block(512);        // 8 waves, 2 per SIMD
  hipLaunchKernelGGL(llrnn_f16, grid, block, 0, stream,
                     in, Km, Rm, bz, Wd, bd, out);
}

// Round 5
// 239.061 us; speedup vs baseline: 8.6675x; 1.3648x over previous
//
#include <hip/hip_runtime.h>

#define BATCH 4096
#define T 256
#define IN 64
#define CELL 128
#define ZDIM 256
#define OUTD 64
#define M 16   // batch rows per block (one MFMA row-tile)

using f32x4 = __attribute__((ext_vector_type(4))) float;
using f4    = __attribute__((ext_vector_type(4))) float;
using h16x8 = __attribute__((ext_vector_type(8))) _Float16;
using fp16x2 = __attribute__((ext_vector_type(2))) __fp16;   // cvt_pkrtz result type
typedef unsigned int u32t;

union h8cast { h16x8 v; fp16x2 h[4]; };

// One recurrence step. Reads c(fp16) from cbuf[P], writes c'(fp16) to cbuf[P^1].
// XC* = raw fp32 x(t) (prefetched last step); prefetches x(t+1) into XN*.
#define STEP(XC0, XC1, XC2, XC3, XN0, XN1, XN2, XN3, TT, P)                     \
  {                                                                             \
    /* prefetch x(t+1) first: longest latency, needed latest */                 \
    {                                                                           \
      int tn = (TT) + 1 < T ? (TT) + 1 : T - 1;                                 \
      const float* xp = xrow + (size_t)tn * IN;                                 \
      XN0 = *(const f4*)(xp + 8 * g);                                           \
      XN1 = *(const f4*)(xp + 8 * g + 4);                                       \
      XN2 = *(const f4*)(xp + 32 + 8 * g);                                      \
      XN3 = *(const f4*)(xp + 32 + 8 * g + 4);                                  \
    }                                                                           \
    /* issue c-frag LDS reads early */                                          \
    const char* cb_ = cbuf[P];                                                  \
    h16x8 ca0 = *(const h16x8*)(cb_ + ro[0]);                                   \
    h16x8 ca1 = *(const h16x8*)(cb_ + ro[1]);                                   \
    h16x8 ca2 = *(const h16x8*)(cb_ + ro[2]);                                   \
    h16x8 ca3 = *(const h16x8*)(cb_ + ro[3]);                                   \
    /* convert x(t) to fp16 A-frags while LDS returns (packed RTZ) */           \
    h8cast ux0, ux1;                                                            \
    ux0.h[0] = __builtin_amdgcn_cvt_pkrtz(XC0[0], XC0[1]);                      \
    ux0.h[1] = __builtin_amdgcn_cvt_pkrtz(XC0[2], XC0[3]);                      \
    ux0.h[2] = __builtin_amdgcn_cvt_pkrtz(XC1[0], XC1[1]);                      \
    ux0.h[3] = __builtin_amdgcn_cvt_pkrtz(XC1[2], XC1[3]);                      \
    ux1.h[0] = __builtin_amdgcn_cvt_pkrtz(XC2[0], XC2[1]);                      \
    ux1.h[1] = __builtin_amdgcn_cvt_pkrtz(XC2[2], XC2[3]);                      \
    ux1.h[2] = __builtin_amdgcn_cvt_pkrtz(XC3[0], XC3[1]);                      \
    ux1.h[3] = __builtin_amdgcn_cvt_pkrtz(XC3[2], XC3[3]);                      \
    const h16x8 xa0 = ux0.v, xa1 = ux1.v;                                       \
    /* two parallel depth-3 MFMA chains per gate */                             \
    f32x4 accfa = {biasf, biasf, biasf, biasf};                                 \
    f32x4 accga = {biasg, biasg, biasg, biasg};                                 \
    f32x4 accfb = {0.f, 0.f, 0.f, 0.f};                                         \
    f32x4 accgb = {0.f, 0.f, 0.f, 0.f};                                         \
    accfa = __builtin_amdgcn_mfma_f32_16x16x32_f16(xa0, bf0, accfa, 0, 0, 0);   \
    accga = __builtin_amdgcn_mfma_f32_16x16x32_f16(xa0, bg0, accga, 0, 0, 0);   \
    accfb = __builtin_amdgcn_mfma_f32_16x16x32_f16(xa1, bf1, accfb, 0, 0, 0);   \
    accgb = __builtin_amdgcn_mfma_f32_16x16x32_f16(xa1, bg1, accgb, 0, 0, 0);   \
    accfa = __builtin_amdgcn_mfma_f32_16x16x32_f16(ca0, bf2, accfa, 0, 0, 0);   \
    accga = __builtin_amdgcn_mfma_f32_16x16x32_f16(ca0, bg2, accga, 0, 0, 0);   \
    accfb = __builtin_amdgcn_mfma_f32_16x16x32_f16(ca1, bf3, accfb, 0, 0, 0);   \
    accgb = __builtin_amdgcn_mfma_f32_16x16x32_f16(ca1, bg3, accgb, 0, 0, 0);   \
    accfa = __builtin_amdgcn_mfma_f32_16x16x32_f16(ca2, bf4, accfa, 0, 0, 0);   \
    accga = __builtin_amdgcn_mfma_f32_16x16x32_f16(ca2, bg4, accga, 0, 0, 0);   \
    accfb = __builtin_amdgcn_mfma_f32_16x16x32_f16(ca3, bf5, accfb, 0, 0, 0);   \
    accgb = __builtin_amdgcn_mfma_f32_16x16x32_f16(ca3, bg5, accgb, 0, 0, 0);   \
    /* gates: f = sigmoid(zf), th = tanh(zg); inf-safe, no clamp needed */      \
    char* cn_ = cbuf[(P) ^ 1];                                                  \
    _Pragma("unroll") for (int i = 0; i < 4; ++i) {                             \
      float zf = accfa[i] + accfb[i];                                           \
      float zg = accga[i] + accgb[i];                                           \
      float fg = __builtin_amdgcn_rcpf(1.f + __expf(-zf));                      \
      float th = 1.f - 2.f * __builtin_amdgcn_rcpf(__expf(2.f * zg) + 1.f);     \
      float cn = fg * (creg[i] - th) + th;                                      \
      creg[i] = cn;                                                             \
      *(_Float16*)(cn_ + wo[i]) = (_Float16)cn;                                 \
    }                                                                           \
    __syncthreads();                                                            \
  }

__global__ __launch_bounds__(512, 2)
void llrnn_f16(const float* __restrict__ in,   // [B,T,IN]
               const float* __restrict__ Km,   // [IN,ZDIM]
               const float* __restrict__ Rm,   // [CELL,ZDIM]
               const float* __restrict__ bz,   // [ZDIM]
               const float* __restrict__ Wd,   // [CELL,OUTD]
               const float* __restrict__ bd,   // [OUTD]
               float* __restrict__ out)        // [B,OUTD]
{
  // c state as fp16 [16 rows][128 cells], chunk-XOR-swizzled, double-buffered.
  __shared__ __align__(16) char cbuf[2][M * CELL * 2];   // 2 x 4 KB
  __shared__ float cfin[M * CELL];

  const int tid = threadIdx.x;
  const int w = tid >> 6;        // wave 0..7: owns z-cols [16w,16w+16) and +128
  const int l = tid & 63;
  const int q = l & 15;          // A-row / D-col within tile
  const int g = l >> 4;          // k-group 0..3
  const int rb = blockIdx.x * M;
  const int jf = 16 * w + q;     // forget-gate column
  const int jg = jf + CELL;      // cell-input column

  // zero c(t=0) buffer
  ((u32t*)cbuf[0])[tid] = 0;
  ((u32t*)cbuf[0])[tid + 512] = 0;

  // ---- preload B = [K; R] columns jf, jg as fp16 fragments (48 VGPR) ----
  h16x8 bf0, bf1, bf2, bf3, bf4, bf5, bg0, bg1, bg2, bg3, bg4, bg5;
#define LOADB(DSTF, DSTG, KT)                                                   \
  {                                                                             \
    _Pragma("unroll") for (int e = 0; e < 8; ++e) {                             \
      const int krow = 32 * (KT) + 8 * g + e;                                   \
      const float* src = ((KT) < 2) ? (Km + (size_t)krow * ZDIM)                \
                                    : (Rm + (size_t)(krow - IN) * ZDIM);        \
      DSTF[e] = (_Float16)src[jf];                                              \
      DSTG[e] = (_Float16)src[jg];                                              \
    }                                                                           \
  }
  LOADB(bf0, bg0, 0) LOADB(bf1, bg1, 1) LOADB(bf2, bg2, 2)
  LOADB(bf3, bg3, 3) LOADB(bf4, bg4, 4) LOADB(bf5, bg5, 5)
#undef LOADB
  // pin B fragments in VGPRs: compiler must not re-derive them from memory
  asm volatile("" : "+v"(bf0), "+v"(bf1), "+v"(bf2), "+v"(bf3), "+v"(bf4),
                    "+v"(bf5), "+v"(bg0), "+v"(bg1), "+v"(bg2), "+v"(bg3),
                    "+v"(bg4), "+v"(bg5));

  const float biasf = bz[jf];
  const float biasg = bz[jg];

  // precomputed LDS byte offsets (chunk-XOR swizzle, involution both sides)
  int ro[4];   // read: c frag kt, row q, k = 32*kt + 8g .. +8
#pragma unroll
  for (int ct = 0; ct < 4; ++ct)
    ro[ct] = q * 256 + 16 * ((4 * ct + g) ^ (q & 7));
  int wo[4];   // write: cell (row 4g+i, k = jf)
#pragma unroll
  for (int i = 0; i < 4; ++i) {
    const int r = 4 * g + i;
    wo[i] = r * 256 + 16 * ((2 * w + (q >> 3)) ^ (r & 7)) + 2 * (q & 7);
  }

  const float* xrow = in + (size_t)(rb + q) * T * IN;
  f4 xc0 = *(const f4*)(xrow + 8 * g);
  f4 xc1 = *(const f4*)(xrow + 8 * g + 4);
  f4 xc2 = *(const f4*)(xrow + 32 + 8 * g);
  f4 xc3 = *(const f4*)(xrow + 32 + 8 * g + 4);
  f4 xn0, xn1, xn2, xn3;

  float creg[4] = {0.f, 0.f, 0.f, 0.f};  // fp32 master state (D-layout)

  __syncthreads();

  for (int t = 0; t < T; t += 2) {
    STEP(xc0, xc1, xc2, xc3, xn0, xn1, xn2, xn3, t, 0)
    STEP(xn0, xn1, xn2, xn3, xc0, xc1, xc2, xc3, t + 1, 1)
  }

  // ---- final c (fp32) to LDS, dense epilogue out = h @ Wd + bd ----
#pragma unroll
  for (int i = 0; i < 4; ++i)
    cfin[(4 * g + i) * CELL + jf] = creg[i];
  __syncthreads();

  const int o = tid & 63;
  const int rp = tid >> 6;  // rows rp and rp+8
  float a0 = bd[o], a1 = bd[o];
#pragma unroll 4
  for (int k = 0; k < CELL; ++k) {
    const float wv = Wd[(size_t)k * OUTD + o];
    a0 += cfin[rp * CELL + k] * wv;
    a1 += cfin[(rp + 8) * CELL + k] * wv;
  }
  out[(size_t)(rb + rp) * OUTD + o] = a0;
  out[(size_t)(rb + rp + 8) * OUTD + o] = a1;
}

extern "C" void kernel_launch(void* const* d_in, const int* in_sizes, int n_in,
                              void* d_out, int out_size, void* d_ws, size_t ws_size,
                              hipStream_t stream) {
  const float* in  = (const float*)d_in[0];
  const float* Km  = (const float*)d_in[1];
  const float* Rm  = (const float*)d_in[2];
  const float* bz  = (const float*)d_in[3];
  const float* Wd  = (const float*)d_in[4];
  const float* bd  = (const float*)d_in[5];
  float* out = (float*)d_out;

  dim3 grid(BATCH / M);   // 256 blocks -> 1 per CU
  dim3 block(512);        // 8 waves, 2 per SIMD
  hipLaunchKernelGGL(llrnn_f16, grid, block, 0, stream,
                     in, Km, Rm, bz, Wd, bd, out);
}